// Round 1
// baseline (1291.409 us; speedup 1.0000x reference)
//
#include <hip/hip_runtime.h>
#include <hip/hip_bf16.h>
#include <cstdint>

#define NROWS 262144
#define HDIM  512
#define NENT  100000

typedef __attribute__((ext_vector_type(4))) float  f32x4;
typedef __attribute__((ext_vector_type(8))) short  bf16x8;

static __device__ __forceinline__ unsigned short f2bf(float x) {
    unsigned u = __float_as_uint(x);
    u += 0x7FFF + ((u >> 16) & 1);          // round-to-nearest-even
    return (unsigned short)(u >> 16);
}

// Pack W (shape [512][1024], y = x @ W.T) into bf16 MFMA B-fragment order:
// for (ntile, ktile32): lane l holds B[k = kt*32+(l>>4)*8+j][col = nt*16+(l&15)]
// = W[col][k], 8 consecutive k per lane -> one 16B load per fragment in the GEMM.
__global__ void pack_w_kernel(const float* __restrict__ W, unsigned short* __restrict__ Wp) {
    int g    = blockIdx.x * 256 + threadIdx.x;   // 65536 total
    int lane = g & 63;
    int task = g >> 6;                            // 0..1023 = nt*32 + kt
    int nt   = task >> 5;
    int kt   = task & 31;
    int col  = nt * 16 + (lane & 15);
    int k    = kt * 32 + ((lane >> 4) << 3);
    const float* src = W + (size_t)col * 1024 + k;
    f32x4 v0 = *(const f32x4*)(src);
    f32x4 v1 = *(const f32x4*)(src + 4);
    bf16x8 ov;
#pragma unroll
    for (int i = 0; i < 4; ++i) {
        ov[i]     = (short)f2bf(v0[i]);
        ov[4 + i] = (short)f2bf(v1[i]);
    }
    *(bf16x8*)(Wp + (size_t)g * 8) = ov;
}

// Fused gate path: 64 rows/block x full 512 cols, K=1024 (emb | LN(state)).
// 512 threads = 8 waves, each wave: 64 rows x 64 cols (4 row-frags x 4 col-frags).
__global__ __launch_bounds__(512) void fuse_kernel(
    const float* __restrict__ emb, const float* __restrict__ slow,
    const unsigned short* __restrict__ Wp, const float* __restrict__ bias,
    const int* __restrict__ ids, float* __restrict__ out,
    float* __restrict__ ctx, unsigned* __restrict__ counts)
{
    __shared__ unsigned short aLds[8 * 512];   // 8 frag-tiles (kt*4+rt), 16B/lane
    __shared__ float muS[64], rsS[64], actS[64], bS[512];
    __shared__ int idS[64];

    const int t    = threadIdx.x;
    const int w    = t >> 6;
    const int lane = t & 63;
    const int brow = blockIdx.x * 64;

    if (t < 128) ((f32x4*)bS)[t] = ((const f32x4*)bias)[t];

    // ---- phase 0: per-row LN stats + is_active + count scatter ----
    for (int rr = 0; rr < 8; ++rr) {
        int row = w * 8 + rr;
        int id  = ids[brow + row];
        const float* sp = slow + (size_t)id * HDIM;
        f32x4 v0 = ((const f32x4*)sp)[lane * 2];
        f32x4 v1 = ((const f32x4*)sp)[lane * 2 + 1];
        float s = 0.f, s2 = 0.f, sa = 0.f;
#pragma unroll
        for (int i = 0; i < 4; ++i) {
            s  += v0[i] + v1[i];
            s2 += v0[i] * v0[i] + v1[i] * v1[i];
            sa += fabsf(v0[i]) + fabsf(v1[i]);
        }
#pragma unroll
        for (int m = 32; m >= 1; m >>= 1) {
            s  += __shfl_xor(s, m);
            s2 += __shfl_xor(s2, m);
            sa += __shfl_xor(sa, m);
        }
        if (lane == 0) {
            float mu  = s * (1.f / HDIM);
            float var = s2 * (1.f / HDIM) - mu * mu;
            muS[row]  = mu;
            rsS[row]  = rsqrtf(var + 1e-5f);
            actS[row] = (sa > 1e-6f) ? 1.f : 0.f;
            idS[row]  = id;
            atomicAdd(&counts[id], 1u);
        }
    }
    __syncthreads();

    // ---- K loop: BK=64, A staged frag-packed in LDS, B frags straight from L2 ----
    const int rowS = t >> 3;            // staging row 0..63
    const int cS   = (t & 7) * 8;       // k offset within BK
    const float* embRow = emb + (size_t)(brow + rowS) * HDIM;
    const float* stRow  = slow + (size_t)idS[rowS] * HDIM;
    const float muR = muS[rowS], rsR = rsS[rowS];

    const int rt_s = rowS >> 4, rl_s = rowS & 15;
    const int kt_s = cS >> 5,  kg_s = (cS >> 3) & 3;
    unsigned short* aDst = &aLds[(kt_s * 4 + rt_s) * 512 + (rl_s + 16 * kg_s) * 8];

    const int c0 = w * 64;
    f32x4 zero4 = {0.f, 0.f, 0.f, 0.f};
    f32x4 acc[4][4];
#pragma unroll
    for (int i = 0; i < 4; ++i)
#pragma unroll
        for (int j = 0; j < 4; ++j) acc[i][j] = zero4;

    for (int ks = 0; ks < 16; ++ks) {
        f32x4 x0, x1;
        int kb = ks * 64 + cS;
        if (ks < 8) {
            x0 = *(const f32x4*)(embRow + kb);
            x1 = *(const f32x4*)(embRow + kb + 4);
        } else {
            x0 = *(const f32x4*)(stRow + kb - 512);
            x1 = *(const f32x4*)(stRow + kb - 512 + 4);
#pragma unroll
            for (int i = 0; i < 4; ++i) {
                x0[i] = (x0[i] - muR) * rsR;
                x1[i] = (x1[i] - muR) * rsR;
            }
        }
        __syncthreads();                 // previous tile's reads done
        bf16x8 av;
#pragma unroll
        for (int i = 0; i < 4; ++i) {
            av[i]     = (short)f2bf(x0[i]);
            av[4 + i] = (short)f2bf(x1[i]);
        }
        *(bf16x8*)aDst = av;
        __syncthreads();                 // tile staged

#pragma unroll
        for (int kk = 0; kk < 2; ++kk) {
            bf16x8 a0 = *(const bf16x8*)&aLds[(kk * 4 + 0) * 512 + lane * 8];
            bf16x8 a1 = *(const bf16x8*)&aLds[(kk * 4 + 1) * 512 + lane * 8];
            bf16x8 a2 = *(const bf16x8*)&aLds[(kk * 4 + 2) * 512 + lane * 8];
            bf16x8 a3 = *(const bf16x8*)&aLds[(kk * 4 + 3) * 512 + lane * 8];
            int kt32 = ks * 2 + kk;
#pragma unroll
            for (int ct = 0; ct < 4; ++ct) {
                int ntile = (c0 >> 4) + ct;
                bf16x8 bfr = *(const bf16x8*)(Wp + ((size_t)(ntile * 32 + kt32) * 64 + lane) * 8);
                acc[0][ct] = __builtin_amdgcn_mfma_f32_16x16x32_bf16(a0, bfr, acc[0][ct], 0, 0, 0);
                acc[1][ct] = __builtin_amdgcn_mfma_f32_16x16x32_bf16(a1, bfr, acc[1][ct], 0, 0, 0);
                acc[2][ct] = __builtin_amdgcn_mfma_f32_16x16x32_bf16(a2, bfr, acc[2][ct], 0, 0, 0);
                acc[3][ct] = __builtin_amdgcn_mfma_f32_16x16x32_bf16(a3, bfr, acc[3][ct], 0, 0, 0);
            }
        }
    }

    // ---- epilogue: sigmoid, fuse, write out, scatter-add ctx ----
#pragma unroll
    for (int rt = 0; rt < 4; ++rt) {
#pragma unroll
        for (int r = 0; r < 4; ++r) {
            int rowl = rt * 16 + ((lane >> 4) * 4) + r;   // C/D: row=(lane>>4)*4+reg
            int grow = brow + rowl;
            int id   = idS[rowl];
            float mu = muS[rowl], rs = rsS[rowl], act = actS[rowl];
#pragma unroll
            for (int ct = 0; ct < 4; ++ct) {
                int col = c0 + ct * 16 + (lane & 15);      // C/D: col=lane&15
                float logit = acc[rt][ct][r] + bS[col];
                float z  = 1.f / (1.f + __expf(-logit));
                float ev = emb[(size_t)grow * HDIM + col];
                float sv = slow[(size_t)id * HDIM + col];
                float h  = (sv - mu) * rs;
                float fused = z * ev + (1.f - z) * h;
                float o  = (act > 0.f) ? fused : ev;
                out[(size_t)grow * HDIM + col] = o;
                atomicAdd(&ctx[(size_t)id * HDIM + col], o);
            }
        }
    }
}

// Per-entity: ctx_sum -> mean -> EMA fast, norm-gated slow. One wave per entity.
__global__ __launch_bounds__(256) void finalize_kernel(
    const float* __restrict__ fast, const float* __restrict__ slow,
    const unsigned* __restrict__ counts, float* __restrict__ nf, float* __restrict__ ns)
{
    int e = blockIdx.x * 4 + (threadIdx.x >> 6);
    if (e >= NENT) return;
    int lane = threadIdx.x & 63;
    size_t base = (size_t)e * HDIM + lane * 8;

    f32x4 s0 = *(f32x4*)(nf + base),       s1 = *(f32x4*)(nf + base + 4);
    f32x4 f0 = *(const f32x4*)(fast + base), f1 = *(const f32x4*)(fast + base + 4);
    f32x4 l0 = *(const f32x4*)(slow + base), l1 = *(const f32x4*)(slow + base + 4);
    unsigned c = counts[e];

    f32x4 n0, n1;
    if (c > 0) {
        float inv = 0.5f / (float)c;       // ALPHA/count
#pragma unroll
        for (int i = 0; i < 4; ++i) {
            n0[i] = 0.5f * f0[i] + s0[i] * inv;
            n1[i] = 0.5f * f1[i] + s1[i] * inv;
        }
    } else { n0 = f0; n1 = f1; }

    f32x4 d0, d1;
    float ss = 0.f;
#pragma unroll
    for (int i = 0; i < 4; ++i) {
        d0[i] = n0[i] - l0[i]; ss += d0[i] * d0[i];
        d1[i] = n1[i] - l1[i]; ss += d1[i] * d1[i];
    }
#pragma unroll
    for (int m = 32; m >= 1; m >>= 1) ss += __shfl_xor(ss, m);
    float delta = sqrtf(ss);
    float gate  = 1.f / (1.f + expf(-5.f * (delta - 0.5f)));

    f32x4 o0, o1;
    if (c > 0) {
#pragma unroll
        for (int i = 0; i < 4; ++i) {
            o0[i] = l0[i] + gate * d0[i];
            o1[i] = l1[i] + gate * d1[i];
        }
    } else { o0 = l0; o1 = l1; }

    *(f32x4*)(nf + base)     = n0;
    *(f32x4*)(nf + base + 4) = n1;
    *(f32x4*)(ns + base)     = o0;
    *(f32x4*)(ns + base + 4) = o1;
}

extern "C" void kernel_launch(void* const* d_in, const int* in_sizes, int n_in,
                              void* d_out, int out_size, void* d_ws, size_t ws_size,
                              hipStream_t stream) {
    const float* emb  = (const float*)d_in[0];
    const float* slow = (const float*)d_in[1];
    const float* fast = (const float*)d_in[2];
    const float* W    = (const float*)d_in[3];
    const float* bias = (const float*)d_in[4];
    const int*   ids  = (const int*)d_in[5];

    float* out = (float*)d_out;
    float* nf  = out + (size_t)NROWS * HDIM;   // new_fast region; doubles as ctx_sum
    float* ns  = nf + (size_t)NENT * HDIM;

    unsigned short* Wp = (unsigned short*)d_ws;                 // 1 MiB packed bf16 W
    unsigned* counts   = (unsigned*)((char*)d_ws + (1 << 20));  // 400 KB counts

    hipMemsetAsync(nf, 0, (size_t)NENT * HDIM * sizeof(float), stream);
    hipMemsetAsync(counts, 0, (size_t)NENT * sizeof(unsigned), stream);

    pack_w_kernel<<<256, 256, 0, stream>>>(W, Wp);
    fuse_kernel<<<NROWS / 64, 512, 0, stream>>>(emb, slow, Wp, bias, ids, out, nf, counts);
    finalize_kernel<<<NENT / 4, 256, 0, stream>>>(fast, slow, counts, nf, ns);
}

// Round 2
// 985.339 us; speedup vs baseline: 1.3106x; 1.3106x over previous
//
#include <hip/hip_runtime.h>
#include <hip/hip_bf16.h>
#include <cstdint>

#define NROWS 262144
#define HDIM  512
#define NENT  100000
#define SCAN_NBLK ((NENT + 1023) / 1024)

typedef __attribute__((ext_vector_type(4))) float  f32x4;
typedef __attribute__((ext_vector_type(8))) short  bf16x8;

static __device__ __forceinline__ unsigned short f2bf(float x) {
    unsigned u = __float_as_uint(x);
    u += 0x7FFF + ((u >> 16) & 1);          // round-to-nearest-even
    return (unsigned short)(u >> 16);
}

// Pack W ([512][1024] row-major, y = x @ W.T) into bf16 MFMA *A*-fragment order:
// for (ntile, kt32): lane l holds A[m = nt*16+(l&15)][k = kt*32+(l>>4)*8+j], i.e.
// W[m][k] -> 8 consecutive k per lane -> one 16B load per fragment in the GEMM.
__global__ void pack_w_kernel(const float* __restrict__ W, unsigned short* __restrict__ Wp) {
    int g    = blockIdx.x * 256 + threadIdx.x;   // 65536 total
    int lane = g & 63;
    int task = g >> 6;                            // 0..1023 = nt*32 + kt
    int nt   = task >> 5;
    int kt   = task & 31;
    int col  = nt * 16 + (lane & 15);
    int k    = kt * 32 + ((lane >> 4) << 3);
    const float* src = W + (size_t)col * 1024 + k;
    f32x4 v0 = *(const f32x4*)(src);
    f32x4 v1 = *(const f32x4*)(src + 4);
    bf16x8 ov;
#pragma unroll
    for (int i = 0; i < 4; ++i) {
        ov[i]     = (short)f2bf(v0[i]);
        ov[4 + i] = (short)f2bf(v1[i]);
    }
    *(bf16x8*)(Wp + (size_t)g * 8) = ov;
}

// ---- CSR build: counts -> 2-level exclusive scan -> fill row indices ----
__global__ __launch_bounds__(256) void count_kernel(const int* __restrict__ ids,
                                                    unsigned* __restrict__ counts) {
    int r = blockIdx.x * 256 + threadIdx.x;
    if (r < NROWS) atomicAdd(&counts[ids[r]], 1u);
}

__global__ __launch_bounds__(1024) void scan1_kernel(const unsigned* __restrict__ counts,
                                                     unsigned* __restrict__ off,
                                                     unsigned* __restrict__ bsums) {
    __shared__ unsigned tmp[1024];
    int i = blockIdx.x * 1024 + threadIdx.x;
    unsigned v = (i < NENT) ? counts[i] : 0u;
    tmp[threadIdx.x] = v;
    __syncthreads();
#pragma unroll
    for (int o = 1; o < 1024; o <<= 1) {
        unsigned a = (threadIdx.x >= o) ? tmp[threadIdx.x - o] : 0u;
        __syncthreads();
        tmp[threadIdx.x] += a;
        __syncthreads();
    }
    if (i < NENT) off[i] = tmp[threadIdx.x] - v;     // block-local exclusive
    if (threadIdx.x == 1023) bsums[blockIdx.x] = tmp[1023];
}

__global__ void scan2_kernel(unsigned* __restrict__ bsums) {
    if (threadIdx.x == 0 && blockIdx.x == 0) {
        unsigned s = 0;
        for (int i = 0; i < SCAN_NBLK; ++i) { unsigned t = bsums[i]; bsums[i] = s; s += t; }
    }
}

__global__ __launch_bounds__(1024) void scan3_kernel(unsigned* __restrict__ off,
                                                     const unsigned* __restrict__ bsums,
                                                     unsigned* __restrict__ cursor) {
    int i = blockIdx.x * 1024 + threadIdx.x;
    if (i < NENT) {
        unsigned o = off[i] + bsums[blockIdx.x];
        off[i] = o;
        cursor[i] = o;
    }
    if (i == 0) off[NENT] = NROWS;
}

__global__ __launch_bounds__(256) void fill_kernel(const int* __restrict__ ids,
                                                   unsigned* __restrict__ cursor,
                                                   int* __restrict__ rowidx) {
    int r = blockIdx.x * 256 + threadIdx.x;
    if (r < NROWS) {
        unsigned p = atomicAdd(&cursor[ids[r]], 1u);
        rowidx[p] = r;
    }
}

// Fused gate path: 64 rows/block x full 512 cols, K=1024 (emb | LN(state)).
// MFMA operands swapped: A = W fragment, B = x fragment -> D holds out^T tiles:
// gate-col m = (lane>>4)*4 + reg (+16*ct), x-row n = lane&15 (+16*rt), so each
// lane owns 4 CONSECUTIVE output columns -> vectorized f32x4 epilogue.
__global__ __launch_bounds__(512) void fuse_kernel(
    const float* __restrict__ emb, const float* __restrict__ slow,
    const unsigned short* __restrict__ Wp, const float* __restrict__ bias,
    const int* __restrict__ ids, float* __restrict__ out)
{
    __shared__ unsigned short aLds[8 * 512];   // 8 frag-tiles (kt*4+rt), 16B/lane
    __shared__ float muS[64], rsS[64], actS[64], bS[512];
    __shared__ int idS[64];

    const int t    = threadIdx.x;
    const int w    = t >> 6;
    const int lane = t & 63;
    const int brow = blockIdx.x * 64;

    if (t < 128) ((f32x4*)bS)[t] = ((const f32x4*)bias)[t];

    // ---- phase 0: per-row LN stats + is_active ----
    for (int rr = 0; rr < 8; ++rr) {
        int row = w * 8 + rr;
        int id  = ids[brow + row];
        const float* sp = slow + (size_t)id * HDIM;
        f32x4 v0 = ((const f32x4*)sp)[lane * 2];
        f32x4 v1 = ((const f32x4*)sp)[lane * 2 + 1];
        float s = 0.f, s2 = 0.f, sa = 0.f;
#pragma unroll
        for (int i = 0; i < 4; ++i) {
            s  += v0[i] + v1[i];
            s2 += v0[i] * v0[i] + v1[i] * v1[i];
            sa += fabsf(v0[i]) + fabsf(v1[i]);
        }
#pragma unroll
        for (int m = 32; m >= 1; m >>= 1) {
            s  += __shfl_xor(s, m);
            s2 += __shfl_xor(s2, m);
            sa += __shfl_xor(sa, m);
        }
        if (lane == 0) {
            float mu  = s * (1.f / HDIM);
            float var = s2 * (1.f / HDIM) - mu * mu;
            muS[row]  = mu;
            rsS[row]  = rsqrtf(var + 1e-5f);
            actS[row] = (sa > 1e-6f) ? 1.f : 0.f;
            idS[row]  = id;
        }
    }
    __syncthreads();

    // ---- K loop: BK=64, A(x) staged frag-packed in LDS, W frags straight from L2 ----
    const int rowS = t >> 3;            // staging row 0..63
    const int kc   = t & 7;             // 8-float k-chunk within BK
    const float* embRow = emb + (size_t)(brow + rowS) * HDIM;
    const float* stRow  = slow + (size_t)idS[rowS] * HDIM;
    const float muR = muS[rowS], rsR = rsS[rowS];

    // swizzled staging position: pos = kg*16 + (rl ^ (kg<<1)) -> write groups hit
    // 4 distinct bank quads (2-way only = free); reads stay contiguous per chunk.
    const int rt_s = rowS >> 4, rl_s = rowS & 15;
    const int kt_s = kc >> 2,  kg_s = kc & 3;
    unsigned short* aDst = &aLds[(kt_s * 4 + rt_s) * 512 + (kg_s * 16 + (rl_s ^ (kg_s << 1))) * 8];
    const int kgr = lane >> 4, rlr = lane & 15;
    const int posr = kgr * 16 + (rlr ^ (kgr << 1));

    const int c0 = w * 64;
    f32x4 zero4 = {0.f, 0.f, 0.f, 0.f};
    f32x4 acc[4][4];                    // [rt = x-row tile][ct = gate-col tile]
#pragma unroll
    for (int i = 0; i < 4; ++i)
#pragma unroll
        for (int j = 0; j < 4; ++j) acc[i][j] = zero4;

    for (int ks = 0; ks < 16; ++ks) {
        f32x4 x0, x1;
        int kb = ks * 64 + kc * 8;
        if (ks < 8) {
            x0 = *(const f32x4*)(embRow + kb);
            x1 = *(const f32x4*)(embRow + kb + 4);
        } else {
            x0 = *(const f32x4*)(stRow + kb - 512);
            x1 = *(const f32x4*)(stRow + kb - 512 + 4);
#pragma unroll
            for (int i = 0; i < 4; ++i) {
                x0[i] = (x0[i] - muR) * rsR;
                x1[i] = (x1[i] - muR) * rsR;
            }
        }
        __syncthreads();                 // previous tile's reads done
        bf16x8 av;
#pragma unroll
        for (int i = 0; i < 4; ++i) {
            av[i]     = (short)f2bf(x0[i]);
            av[4 + i] = (short)f2bf(x1[i]);
        }
        *(bf16x8*)aDst = av;
        __syncthreads();                 // tile staged

#pragma unroll
        for (int kk = 0; kk < 2; ++kk) {
            bf16x8 a0 = *(const bf16x8*)&aLds[(kk * 4 + 0) * 512 + posr * 8];
            bf16x8 a1 = *(const bf16x8*)&aLds[(kk * 4 + 1) * 512 + posr * 8];
            bf16x8 a2 = *(const bf16x8*)&aLds[(kk * 4 + 2) * 512 + posr * 8];
            bf16x8 a3 = *(const bf16x8*)&aLds[(kk * 4 + 3) * 512 + posr * 8];
            int kt32 = ks * 2 + kk;
#pragma unroll
            for (int ct = 0; ct < 4; ++ct) {
                int ntile = (c0 >> 4) + ct;
                bf16x8 bfr = *(const bf16x8*)(Wp + ((size_t)(ntile * 32 + kt32) * 64 + lane) * 8);
                acc[0][ct] = __builtin_amdgcn_mfma_f32_16x16x32_bf16(bfr, a0, acc[0][ct], 0, 0, 0);
                acc[1][ct] = __builtin_amdgcn_mfma_f32_16x16x32_bf16(bfr, a1, acc[1][ct], 0, 0, 0);
                acc[2][ct] = __builtin_amdgcn_mfma_f32_16x16x32_bf16(bfr, a2, acc[2][ct], 0, 0, 0);
                acc[3][ct] = __builtin_amdgcn_mfma_f32_16x16x32_bf16(bfr, a3, acc[3][ct], 0, 0, 0);
            }
        }
    }

    // ---- epilogue: sigmoid, fuse, vectorized f32x4 writes ----
#pragma unroll
    for (int rt = 0; rt < 4; ++rt) {
        int rowl = rt * 16 + (lane & 15);
        int grow = brow + rowl;
        int id   = idS[rowl];
        float mu = muS[rowl], rs = rsS[rowl], act = actS[rowl];
        const float* embP  = emb  + (size_t)grow * HDIM;
        const float* slowP = slow + (size_t)id * HDIM;
        float*       outP  = out  + (size_t)grow * HDIM;
#pragma unroll
        for (int ct = 0; ct < 4; ++ct) {
            int col0 = c0 + ct * 16 + ((lane >> 4) << 2);
            f32x4 bv = *(const f32x4*)&bS[col0];
            f32x4 ev = *(const f32x4*)(embP + col0);
            f32x4 sv = *(const f32x4*)(slowP + col0);
            f32x4 o;
#pragma unroll
            for (int r = 0; r < 4; ++r) {
                float logit = acc[rt][ct][r] + bv[r];
                float z  = 1.f / (1.f + __expf(-logit));
                float h  = (sv[r] - mu) * rs;
                float fused = z * ev[r] + (1.f - z) * h;
                o[r] = (act > 0.f) ? fused : ev[r];
            }
            *(f32x4*)(outP + col0) = o;
        }
    }
}

// Per-entity: gather its rows from `out` (CSR), mean -> EMA fast, norm-gated slow.
__global__ __launch_bounds__(256) void finalize_kernel(
    const float* __restrict__ fast, const float* __restrict__ slow,
    const float* __restrict__ out, const unsigned* __restrict__ off,
    const int* __restrict__ rowidx, float* __restrict__ nf, float* __restrict__ ns)
{
    int e = blockIdx.x * 4 + (threadIdx.x >> 6);
    if (e >= NENT) return;
    int lane = threadIdx.x & 63;
    size_t base = (size_t)e * HDIM + lane * 8;

    f32x4 f0 = *(const f32x4*)(fast + base), f1 = *(const f32x4*)(fast + base + 4);
    f32x4 l0 = *(const f32x4*)(slow + base), l1 = *(const f32x4*)(slow + base + 4);

    unsigned o0 = off[e], o1 = off[e + 1];
    int c = (int)(o1 - o0);

    if (c == 0) {
        *(f32x4*)(nf + base)     = f0;
        *(f32x4*)(nf + base + 4) = f1;
        *(f32x4*)(ns + base)     = l0;
        *(f32x4*)(ns + base + 4) = l1;
        return;
    }

    f32x4 s0 = {0.f, 0.f, 0.f, 0.f}, s1 = {0.f, 0.f, 0.f, 0.f};
    for (int j = 0; j < c; ++j) {
        int r = rowidx[o0 + j];
        const float* p = out + (size_t)r * HDIM + lane * 8;
        s0 += *(const f32x4*)p;
        s1 += *(const f32x4*)(p + 4);
    }

    float inv = 0.5f / (float)c;          // ALPHA / count
    f32x4 n0, n1, d0, d1;
    float ss = 0.f;
#pragma unroll
    for (int i = 0; i < 4; ++i) {
        n0[i] = 0.5f * f0[i] + s0[i] * inv;
        n1[i] = 0.5f * f1[i] + s1[i] * inv;
        d0[i] = n0[i] - l0[i]; ss += d0[i] * d0[i];
        d1[i] = n1[i] - l1[i]; ss += d1[i] * d1[i];
    }
#pragma unroll
    for (int m = 32; m >= 1; m >>= 1) ss += __shfl_xor(ss, m);
    float delta = sqrtf(ss);
    float gate  = 1.f / (1.f + expf(-5.f * (delta - 0.5f)));

    f32x4 o0v, o1v;
#pragma unroll
    for (int i = 0; i < 4; ++i) {
        o0v[i] = l0[i] + gate * d0[i];
        o1v[i] = l1[i] + gate * d1[i];
    }
    *(f32x4*)(nf + base)     = n0;
    *(f32x4*)(nf + base + 4) = n1;
    *(f32x4*)(ns + base)     = o0v;
    *(f32x4*)(ns + base + 4) = o1v;
}

extern "C" void kernel_launch(void* const* d_in, const int* in_sizes, int n_in,
                              void* d_out, int out_size, void* d_ws, size_t ws_size,
                              hipStream_t stream) {
    const float* emb  = (const float*)d_in[0];
    const float* slow = (const float*)d_in[1];
    const float* fast = (const float*)d_in[2];
    const float* W    = (const float*)d_in[3];
    const float* bias = (const float*)d_in[4];
    const int*   ids  = (const int*)d_in[5];

    float* out = (float*)d_out;
    float* nf  = out + (size_t)NROWS * HDIM;
    float* ns  = nf + (size_t)NENT * HDIM;

    // ws layout: Wp 1 MiB | counts/cursor 400 KB | offsets 400 KB | bsums | rowidx 1 MiB
    unsigned short* Wp   = (unsigned short*)d_ws;
    unsigned* counts     = (unsigned*)((char*)d_ws + (1u << 20));            // reused as cursor
    unsigned* off        = (unsigned*)((char*)d_ws + (1u << 20) + 512 * 1024);
    unsigned* bsums      = (unsigned*)((char*)d_ws + (2u << 20));
    int*      rowidx     = (int*)((char*)d_ws + (2u << 20) + 4096);

    hipMemsetAsync(counts, 0, (size_t)NENT * sizeof(unsigned), stream);

    pack_w_kernel<<<256, 256, 0, stream>>>(W, Wp);
    count_kernel<<<NROWS / 256, 256, 0, stream>>>(ids, counts);
    scan1_kernel<<<SCAN_NBLK, 1024, 0, stream>>>(counts, off, bsums);
    scan2_kernel<<<1, 64, 0, stream>>>(bsums);
    scan3_kernel<<<SCAN_NBLK, 1024, 0, stream>>>(off, bsums, counts);
    fill_kernel<<<NROWS / 256, 256, 0, stream>>>(ids, counts, rowidx);
    fuse_kernel<<<NROWS / 64, 512, 0, stream>>>(emb, slow, Wp, bias, ids, out);
    finalize_kernel<<<(NENT + 3) / 4, 256, 0, stream>>>(fast, slow, out, off, rowidx, nf, ns);
}